// Round 8
// baseline (1848.355 us; speedup 1.0000x reference)
//
#include <hip/hip_runtime.h>

#define L_ 256
#define B_ 256
#define V_ 50000
#define E_ 300
#define H_ 256
#define T_ 17
#define G4 1024  // 4*H

typedef short short8 __attribute__((ext_vector_type(8)));
typedef float f32x4 __attribute__((ext_vector_type(4)));
typedef float f32x2 __attribute__((ext_vector_type(2)));
typedef unsigned long long ull;

// barrier that does NOT drain vmcnt: LDS ordering only (lgkmcnt), so global
// prefetch loads / fire-and-forget stores stay in flight across it.
#define BARRIER_LDS() asm volatile("s_waitcnt lgkmcnt(0)\n\ts_barrier" ::: "memory")

static __device__ __forceinline__ short f2bf(float x) {
    unsigned int u = __float_as_uint(x);
    u = (u + 0x7fffu + ((u >> 16) & 1u)) >> 16;   // RNE to bf16
    return (short)u;
}
static __device__ __forceinline__ float bf2f(unsigned int u) {
    return __uint_as_float(u << 16);
}

#if __has_builtin(__builtin_amdgcn_exp2f)
#define EXP2(x) __builtin_amdgcn_exp2f(x)
#else
#define EXP2(x) __expf(0.6931471805599453f * (x))
#endif
#if __has_builtin(__builtin_amdgcn_rcpf)
#define RCP(x) __builtin_amdgcn_rcpf(x)
#else
#define RCP(x) (1.0f / (x))
#endif

static __device__ __forceinline__ float sigm(float x) {
    return RCP(1.0f + EXP2(-1.4426950408889634f * x));
}
static __device__ __forceinline__ float tanh_(float x) {
    return fmaf(-2.0f, RCP(EXP2(2.8853900817779268f * x) + 1.0f), 1.0f);
}

// f32 -> OCP e4m3fn, RNE, finite input; clamps to +-448. (fallback path)
static __device__ __forceinline__ unsigned int f2fp8(float x) {
    float ax = fminf(fabsf(x), 448.0f);
    int e = (int)(__float_as_uint(ax) >> 23) - 127;
    int ec = e < -6 ? -6 : e;
    float sc = __uint_as_float((unsigned int)(130 - ec) << 23);
    float t = __builtin_fmaf(ax, sc, 12582912.0f);
    int n = (int)(__float_as_uint(t) & 0x3fffff);
    int code = ((ec + 7) << 3) + n - 8;
    return (unsigned int)code | ((__float_as_uint(x) >> 24) & 0x80);
}
static __device__ __forceinline__ unsigned int pk_fp8(float a, float b) {
#if __has_builtin(__builtin_amdgcn_cvt_pk_fp8_f32)
    return (unsigned int)__builtin_amdgcn_cvt_pk_fp8_f32(a, b, 0, false) & 0xffffu;
#else
    return f2fp8(a) | (f2fp8(b) << 8);
#endif
}
static __device__ __forceinline__ float dec8(unsigned int b) {
    unsigned int f = ((b & 0x7fu) << 20) + 0x3C000000u;
    f |= (b & 0x80u) << 24;
    return __uint_as_float(f);
}
template <bool HI>
static __device__ __forceinline__ f32x2 pk_f32(unsigned int u) {
#if __has_builtin(__builtin_amdgcn_cvt_pk_f32_fp8)
    return __builtin_amdgcn_cvt_pk_f32_fp8((int)u, HI);
#else
    f32x2 r;
    r.x = dec8((u >> (HI ? 16 : 0)) & 0xff);
    r.y = dec8((u >> (HI ? 24 : 8)) & 0xff);
    return r;
#endif
}

// pack two f32 -> bf16 pair (round-half-up via +0x8000, then byte-perm)
static __device__ __forceinline__ unsigned int pk2bf(float x, float y) {
#if __has_builtin(__builtin_amdgcn_perm)
    return __builtin_amdgcn_perm(__float_as_uint(y) + 0x8000u,
                                 __float_as_uint(x) + 0x8000u, 0x07060302u);
#else
    return (unsigned int)(unsigned short)f2bf(x) |
           ((unsigned int)(unsigned short)f2bf(y) << 16);
#endif
}
static __device__ __forceinline__ short8 pack8(float4 a, float4 b) {
    union { unsigned int u[4]; short8 s; } r;
    r.u[0] = pk2bf(a.x, a.y);
    r.u[1] = pk2bf(a.z, a.w);
    r.u[2] = pk2bf(b.x, b.y);
    r.u[3] = pk2bf(b.z, b.w);
    return r.s;
}

// ---------------------------------------------------------------------------
// prep_w: single launch for all weight packing.
//   gid <  524288          : w_hh (both dirs, x8)  -> fp8 LSTM B-frags
//   gid <  540672          : lin_w (x32)           -> fp8 emission B-frags
//   gid < 1196032          : w_ih (both dirs)      -> bf16 tg_gemm B-frags
// ---------------------------------------------------------------------------
__global__ __launch_bounds__(256) void prep_w(const float* __restrict__ whf,
                                              const float* __restrict__ whb,
                                              const float* __restrict__ lin_w,
                                              const float* __restrict__ w_ih_f,
                                              const float* __restrict__ w_ih_b,
                                              unsigned char* __restrict__ wB8,
                                              unsigned char* __restrict__ linB8,
                                              unsigned short* __restrict__ wBihF,
                                              unsigned short* __restrict__ wBihB) {
    int gid = blockIdx.x * 256 + threadIdx.x;
    if (gid < 524288) {
        int j = gid & 7;
        int lane = (gid >> 3) & 63;
        int gt = (gid >> 9) & 3;
        int kt = (gid >> 11) & 7;
        int wv = (gid >> 14) & 15;
        int dir = gid >> 18;
        int g = gt * 256 + wv * 16 + (lane & 15);
        int k = kt * 32 + (lane >> 4) * 8 + j;
        const float* w = dir ? whb : whf;
        wB8[gid] = (unsigned char)f2fp8(w[g * H_ + k] * 8.0f);
    } else if (gid < 540672) {
        int i2 = gid - 524288;  // < 16384
        int dir = (i2 >> 13) & 1;
        int wv = (i2 >> 12) & 1;
        int kt = (i2 >> 9) & 7;
        int lane = (i2 >> 3) & 63;
        int j = i2 & 7;
        int t = wv * 16 + (lane & 15);
        int k = kt * 32 + (lane >> 4) * 8 + j;
        float v = (t < T_) ? lin_w[t * (2 * H_) + dir * H_ + k] * 32.0f : 0.0f;
        linB8[i2] = (unsigned char)f2fp8(v);
    } else {
        int i3 = gid - 540672;  // < 655360
        int dir = i3 >= 327680;
        int i = i3 - dir * 327680;
        int gtile = i / 5120;
        int r = i - gtile * 5120;
        int kt = r >> 9;
        int lane = (r >> 3) & 63;
        int j = r & 7;
        int g = gtile * 16 + (lane & 15);
        int k = kt * 32 + (lane >> 4) * 8 + j;
        const float* src = dir ? w_ih_b : w_ih_f;
        unsigned short* dst = dir ? wBihB : wBihF;
        dst[i] = (unsigned short)((k < E_) ? f2bf(src[g * E_ + k]) : (short)0);
    }
}

// ---------------------------------------------------------------------------
// tg_gemm v5: v4 structure + 2-deep A/B prefetch + lgkm-only barrier so the
// global prefetch stays in flight across the per-kt barrier (no vmcnt drain).
// Grid (196, 8); block = 512 thr / 8 waves; 256 rows x (2 jt-cols x 4 gates
// x 2 dirs). Epilogue: one dword per (v, hidden j) = packed {i,f,g,o} fp8.
// ---------------------------------------------------------------------------
__global__ __launch_bounds__(512, 2) void tg_gemm(const float* __restrict__ table,
                                                  const unsigned short* __restrict__ wBihF,
                                                  const unsigned short* __restrict__ wBihB,
                                                  const float* __restrict__ b_ih_f,
                                                  const float* __restrict__ b_hh_f,
                                                  const float* __restrict__ b_ih_b,
                                                  const float* __restrict__ b_hh_b,
                                                  unsigned char* __restrict__ tg8) {
    __shared__ __align__(16) unsigned short Bs[2][16][512];
    const int tid = threadIdx.x;
    const int w = tid >> 6;
    const int lane = tid & 63;
    const int n = lane & 15;
    const int q = lane >> 4;
    const int jt0 = blockIdx.y * 2;
    const int v0 = blockIdx.x * 256 + w * 32;

    const int r0 = v0 + n;
    const int r1 = v0 + 16 + n;
    const float* arow0 = table + (size_t)(r0 < V_ ? r0 : V_ - 1) * E_;
    const float* arow1 = table + (size_t)(r1 < V_ ? r1 : V_ - 1) * E_;

    // this wave stages frags f = w and w+8;  f = dir*8 + jj*4 + gt
    const unsigned short* bsrc[2];
#pragma unroll
    for (int s = 0; s < 2; ++s) {
        const int f = w + s * 8;
        const int dir = f >> 3, jj = (f >> 2) & 1, gt = f & 3;
        const int gtile = gt * 16 + jt0 + jj;
        bsrc[s] = (dir ? wBihB : wBihF) + (size_t)gtile * 5120 + lane * 8;
    }

    f32x4 acc[2][4][2][2];  // [jj][gt][rt][dir]
#pragma unroll
    for (int jj = 0; jj < 2; ++jj)
#pragma unroll
        for (int gt = 0; gt < 4; ++gt)
#pragma unroll
            for (int rt = 0; rt < 2; ++rt)
#pragma unroll
                for (int d = 0; d < 2; ++d)
                    acc[jj][gt][rt][d] = (f32x4){0.f, 0.f, 0.f, 0.f};

    // 2-deep prefetch pipeline
    float4 apre[2][4];
    short8 bpre[2][2];
#pragma unroll
    for (int s = 0; s < 2; ++s) {  // kt = 0, 1 (both full tiles)
        const int e0 = s * 32 + q * 8;
        apre[s][0] = *(const float4*)(arow0 + e0);
        apre[s][1] = *(const float4*)(arow0 + e0 + 4);
        apre[s][2] = *(const float4*)(arow1 + e0);
        apre[s][3] = *(const float4*)(arow1 + e0 + 4);
        bpre[s][0] = *(const short8*)(bsrc[0] + s * 512);
        bpre[s][1] = *(const short8*)(bsrc[1] + s * 512);
    }

#pragma unroll 1
    for (int kt = 0; kt < 10; ++kt) {
        const int cur = kt & 1;
        *(short8*)&Bs[cur][w][lane * 8] = bpre[cur][0];
        *(short8*)&Bs[cur][w + 8][lane * 8] = bpre[cur][1];
        BARRIER_LDS();

        const short8 af0 = pack8(apre[cur][0], apre[cur][1]);
        const short8 af1 = pack8(apre[cur][2], apre[cur][3]);

        if (kt + 2 < 10) {
            const int ktn = kt + 2;
            const int e0n = ktn * 32 + q * 8;
            if (ktn < 9) {
                apre[cur][0] = *(const float4*)(arow0 + e0n);
                apre[cur][1] = *(const float4*)(arow0 + e0n + 4);
                apre[cur][2] = *(const float4*)(arow1 + e0n);
                apre[cur][3] = *(const float4*)(arow1 + e0n + 4);
            } else {  // ktn == 9: K tail [288,320), guard e<300 (B is zero there)
                float va[8], vb[8];
#pragma unroll
                for (int j = 0; j < 8; ++j) {
                    const int e = e0n + j;
                    va[j] = (e < E_) ? arow0[e] : 0.0f;
                    vb[j] = (e < E_) ? arow1[e] : 0.0f;
                }
                apre[cur][0] = (float4){va[0], va[1], va[2], va[3]};
                apre[cur][1] = (float4){va[4], va[5], va[6], va[7]};
                apre[cur][2] = (float4){vb[0], vb[1], vb[2], vb[3]};
                apre[cur][3] = (float4){vb[4], vb[5], vb[6], vb[7]};
            }
            bpre[cur][0] = *(const short8*)(bsrc[0] + ktn * 512);
            bpre[cur][1] = *(const short8*)(bsrc[1] + ktn * 512);
        }

#pragma unroll
        for (int f = 0; f < 16; ++f) {
            const int dir = f >> 3, jj = (f >> 2) & 1, gt = f & 3;
            const short8 bf = *(const short8*)&Bs[cur][f][lane * 8];
            acc[jj][gt][0][dir] = __builtin_amdgcn_mfma_f32_16x16x32_bf16(af0, bf, acc[jj][gt][0][dir], 0, 0, 0);
            acc[jj][gt][1][dir] = __builtin_amdgcn_mfma_f32_16x16x32_bf16(af1, bf, acc[jj][gt][1][dir], 0, 0, 0);
        }
    }

    // epilogue: bias, scale x64, pack {i,f,g,o} -> one dword per (v, j)
    float bias[2][2][4];  // [dir][jj][gt]
#pragma unroll
    for (int d = 0; d < 2; ++d)
#pragma unroll
        for (int jj = 0; jj < 2; ++jj)
#pragma unroll
            for (int gt = 0; gt < 4; ++gt) {
                const int g = gt * 256 + (jt0 + jj) * 16 + n;
                bias[d][jj][gt] = d ? (b_ih_b[g] + b_hh_b[g]) : (b_ih_f[g] + b_hh_f[g]);
            }

#pragma unroll
    for (int d = 0; d < 2; ++d) {
        unsigned int* tgd = (unsigned int*)(tg8 + (size_t)d * 51200000);
#pragma unroll
        for (int jj = 0; jj < 2; ++jj) {
            const int dcol = (jt0 + jj) * 16 + n;  // dword index within row
#pragma unroll
            for (int rt = 0; rt < 2; ++rt) {
#pragma unroll
                for (int r = 0; r < 4; ++r) {
                    const int v = v0 + rt * 16 + q * 4 + r;
                    if (v < V_) {
                        const float x0 = (acc[jj][0][rt][d][r] + bias[d][jj][0]) * 64.0f;
                        const float x1 = (acc[jj][1][rt][d][r] + bias[d][jj][1]) * 64.0f;
                        const float x2 = (acc[jj][2][rt][d][r] + bias[d][jj][2]) * 64.0f;
                        const float x3 = (acc[jj][3][rt][d][r] + bias[d][jj][3]) * 64.0f;
                        tgd[(size_t)v * 256 + dcol] = pk_fp8(x0, x1) | (pk_fp8(x2, x3) << 16);
                    }
                }
            }
        }
    }
}

// ---------------------------------------------------------------------------
// Merged fp8 LSTM (round-6 verified math). Per-step barrier is now lgkm-only:
// the tg gather prefetch + em stores stay in flight across it, so the gather
// gets a full step of latency cover instead of being drained at the barrier.
// ---------------------------------------------------------------------------
__global__ __launch_bounds__(1024, 4) void lstm_fp8(const unsigned char* __restrict__ tg8,
                                                    const ull* __restrict__ wB8,
                                                    const int* __restrict__ words,
                                                    const ull* __restrict__ linB8,
                                                    unsigned short* __restrict__ emf,
                                                    unsigned short* __restrict__ emb) {
    __shared__ __align__(16) unsigned char hbuf[2][16][264];
    const int tid = threadIdx.x;
    const int wv = tid >> 6;
    const int lane = tid & 63;
    const int n = lane & 15;
    const int q = lane >> 4;
    const int dir = blockIdx.x >> 4;
    const int b0 = (blockIdx.x & 15) * 16;

    for (int i = tid; i < 2 * 16 * 264; i += 1024) (&hbuf[0][0][0])[i] = 0;
    __syncthreads();

    float cst[4] = {0.f, 0.f, 0.f, 0.f};

    const int l0 = dir ? (L_ - 1) : 0;
    const int dl = dir ? -1 : 1;

    ull wfrag[32];
    {
        const ull* wbase = wB8 + (size_t)dir * 32768 + (size_t)wv * 2048 + lane;
#pragma unroll
        for (int i = 0; i < 32; ++i) wfrag[i] = wbase[i * 64];
    }

    const unsigned char* tgd = tg8 + (size_t)dir * 51200000;
    const unsigned int laneoff = wv * 64 + n * 4;
    unsigned short* emx = dir ? emb : emf;
    const ull* lfrag = linB8 + (size_t)(dir * 2 + wv) * 512 + lane;
    const int t_em = wv * 16 + n;

    const float kSig = -1.4426950408889634f / 64.0f;
    const float kTanh = 2.8853900817779268f / 64.0f;

    unsigned int tgr[4];
    int4 wnxt;
    {
        const int4 w04 = *(const int4*)&words[l0 * B_ + b0 + q * 4];
        tgr[0] = *(const unsigned int*)(tgd + (((unsigned)w04.x << 10) + laneoff));
        tgr[1] = *(const unsigned int*)(tgd + (((unsigned)w04.y << 10) + laneoff));
        tgr[2] = *(const unsigned int*)(tgd + (((unsigned)w04.z << 10) + laneoff));
        tgr[3] = *(const unsigned int*)(tgd + (((unsigned)w04.w << 10) + laneoff));
        wnxt = *(const int4*)&words[(l0 + dl) * B_ + b0 + q * 4];
    }

    int p = 0;
    for (int step = 0; step < L_; ++step) {
        const int l = l0 + dl * step;
        f32x4 acc[4];
#pragma unroll
        for (int r = 0; r < 4; ++r) {
            f32x2 p0 = pk_f32<false>(tgr[r]);
            f32x2 p1 = pk_f32<true>(tgr[r]);
            acc[0][r] = p0.x; acc[1][r] = p0.y; acc[2][r] = p1.x; acc[3][r] = p1.y;
        }

        if (step + 1 < L_) {
            tgr[0] = *(const unsigned int*)(tgd + (((unsigned)wnxt.x << 10) + laneoff));
            tgr[1] = *(const unsigned int*)(tgd + (((unsigned)wnxt.y << 10) + laneoff));
            tgr[2] = *(const unsigned int*)(tgd + (((unsigned)wnxt.z << 10) + laneoff));
            tgr[3] = *(const unsigned int*)(tgd + (((unsigned)wnxt.w << 10) + laneoff));
        }
        int4 wtmp = {0, 0, 0, 0};
        if (step + 2 < L_) {
            wtmp = *(const int4*)&words[(l + 2 * dl) * B_ + b0 + q * 4];
        }

#pragma unroll
        for (int kt = 0; kt < 8; ++kt) {
            const ull af = *(const ull*)&hbuf[p][n][kt * 32 + q * 8];
#pragma unroll
            for (int gt = 0; gt < 4; ++gt)
                acc[gt] = __builtin_amdgcn_mfma_f32_16x16x32_fp8_fp8(
                    (long long)af, (long long)wfrag[kt * 4 + gt], acc[gt], 0, 0, 0);
        }

        float hv[4];
#pragma unroll
        for (int r = 0; r < 4; ++r) {
            const float ig = RCP(1.0f + EXP2(acc[0][r] * kSig));
            const float fg = RCP(1.0f + EXP2(acc[1][r] * kSig));
            const float gg = fmaf(-2.0f, RCP(EXP2(acc[2][r] * kTanh) + 1.0f), 1.0f);
            const float og = RCP(1.0f + EXP2(acc[3][r] * kSig));
            const float cn = fmaf(fg, cst[r], ig * gg);
            cst[r] = cn;
            hv[r] = og * tanh_(cn);
        }
        {
            const unsigned int p01 = pk_fp8(hv[0] * 8.0f, hv[1] * 8.0f);
            const unsigned int p23 = pk_fp8(hv[2] * 8.0f, hv[3] * 8.0f);
            hbuf[p ^ 1][q * 4 + 0][wv * 16 + n] = (unsigned char)(p01 & 0xff);
            hbuf[p ^ 1][q * 4 + 1][wv * 16 + n] = (unsigned char)(p01 >> 8);
            hbuf[p ^ 1][q * 4 + 2][wv * 16 + n] = (unsigned char)(p23 & 0xff);
            hbuf[p ^ 1][q * 4 + 3][wv * 16 + n] = (unsigned char)(p23 >> 8);
        }
        BARRIER_LDS();   // lgkm-only: tg prefetch + em stores stay outstanding

        if (wv < 2) {
            f32x4 eacc = (f32x4){0.f, 0.f, 0.f, 0.f};
#pragma unroll
            for (int kt = 0; kt < 8; ++kt) {
                const ull af = *(const ull*)&hbuf[p ^ 1][n][kt * 32 + q * 8];
                eacc = __builtin_amdgcn_mfma_f32_16x16x32_fp8_fp8(
                    (long long)af, (long long)lfrag[kt * 64], eacc, 0, 0, 0);
            }
            if (t_em < T_) {
                const size_t embase = ((size_t)l * B_ + b0) * T_ + t_em + (size_t)q * 4 * T_;
#pragma unroll
                for (int r = 0; r < 4; ++r)
                    emx[embase + r * T_] = (unsigned short)f2bf(eacc[r] * (1.0f / 256.0f));
            }
        }

        wnxt = wtmp;
        p ^= 1;
    }
}

// ---------------------------------------------------------------------------
// CRF: one wave per sequence (verified — frozen).
// ---------------------------------------------------------------------------
__global__ __launch_bounds__(64) void crf_kernel(const unsigned short* __restrict__ emf,
                                                 const unsigned short* __restrict__ emb,
                                                 const int* __restrict__ tags,
                                                 const int* __restrict__ mask,
                                                 const float* __restrict__ start_trans,
                                                 const float* __restrict__ end_trans,
                                                 const float* __restrict__ trans,
                                                 const float* __restrict__ lin_b,
                                                 float* __restrict__ llh) {
    const int b = blockIdx.x;
    const int t = threadIdx.x;
    __shared__ float tr[T_ * T_];
    __shared__ float lb[T_];
    for (int i = t; i < T_ * T_; i += 64) tr[i] = trans[i];
    if (t < T_) lb[t] = lin_b[t];
    __syncthreads();

    const int tc = (t < T_) ? t : (T_ - 1);
    const float lbc = lb[tc];
    float trc[T_];
#pragma unroll
    for (int s = 0; s < T_; ++s) trc[s] = tr[s * T_ + tc];

    float part = 0.0f;
    int msum = 0;
    for (int l = t; l < L_; l += 64) {
        const int idx = l * B_ + b;
        const int m = mask[idx];
        msum += m;
        const int tl = tags[idx];
        const float emt = bf2f(emf[(size_t)idx * T_ + tl]) + bf2f(emb[(size_t)idx * T_ + tl]) + lb[tl];
        if (l == 0) {
            part += start_trans[tl] + emt;
        } else {
            const int tp = tags[(l - 1) * B_ + b];
            part += m ? (tr[tp * T_ + tl] + emt) : 0.0f;
        }
    }
    for (int o = 32; o; o >>= 1) {
        part += __shfl_down(part, o);
        msum += __shfl_down(msum, o);
    }
    const int len = __shfl(msum, 0);

    float alpha = start_trans[tc] + bf2f(emf[(size_t)b * T_ + tc]) + bf2f(emb[(size_t)b * T_ + tc]) + lbc;
    float env = 0.0f;
    if (len > 1) {
        const size_t i1 = ((size_t)B_ + b) * T_ + tc;
        env = bf2f(emf[i1]) + bf2f(emb[i1]) + lbc;
    }
    for (int l = 1; l < len; ++l) {
        const float cur = env;
        if (l + 1 < len) {
            const size_t ix = ((size_t)(l + 1) * B_ + b) * T_ + tc;
            env = bf2f(emf[ix]) + bf2f(emb[ix]) + lbc;
        }
        float mx = -1e30f;
#pragma unroll
        for (int s = 0; s < T_; ++s) {
            const float as = __shfl(alpha, s);
            mx = fmaxf(mx, as + trc[s]);
        }
        float sm = 0.0f;
#pragma unroll
        for (int s = 0; s < T_; ++s) {
            const float as = __shfl(alpha, s);
            sm += __expf(as + trc[s] - mx);
        }
        alpha = mx + __logf(sm) + cur;
    }
    float val = (t < T_) ? (alpha + end_trans[t]) : -1e30f;
    float mx = val;
    for (int o = 32; o; o >>= 1) mx = fmaxf(mx, __shfl_down(mx, o));
    const float mx_all = __shfl(mx, 0);
    float sm = __expf(val - mx_all);
    for (int o = 32; o; o >>= 1) sm += __shfl_down(sm, o);

    if (t == 0) {
        const float score = part + end_trans[tags[(len - 1) * B_ + b]];
        const float logZ = mx_all + __logf(sm);
        llh[b] = score - logZ;
    }
}

__global__ __launch_bounds__(256) void final_reduce(const float* __restrict__ llh,
                                                    float* __restrict__ out) {
    const int t = threadIdx.x;
    float v = llh[t];
    for (int o = 32; o; o >>= 1) v += __shfl_down(v, o);
    __shared__ float wsum[4];
    if ((t & 63) == 0) wsum[t >> 6] = v;
    __syncthreads();
    if (t == 0) out[0] = -(wsum[0] + wsum[1] + wsum[2] + wsum[3]);
}

// ---------------------------------------------------------------------------
extern "C" void kernel_launch(void* const* d_in, const int* in_sizes, int n_in,
                              void* d_out, int out_size, void* d_ws, size_t ws_size,
                              hipStream_t stream) {
    const int* words = (const int*)d_in[0];
    const int* tags = (const int*)d_in[1];
    const int* mask = (const int*)d_in[2];
    const float* table = (const float*)d_in[3];
    const float* w_ih_f = (const float*)d_in[4];
    const float* w_hh_f = (const float*)d_in[5];
    const float* b_ih_f = (const float*)d_in[6];
    const float* b_hh_f = (const float*)d_in[7];
    const float* w_ih_b = (const float*)d_in[8];
    const float* w_hh_b = (const float*)d_in[9];
    const float* b_ih_b = (const float*)d_in[10];
    const float* b_hh_b = (const float*)d_in[11];
    const float* lin_w = (const float*)d_in[12];
    const float* lin_b = (const float*)d_in[13];
    const float* start_trans = (const float*)d_in[14];
    const float* end_trans = (const float*)d_in[15];
    const float* trans = (const float*)d_in[16];

    char* ws = (char*)d_ws;
    unsigned char* tg8 = (unsigned char*)ws;                    // 102,400,000 (2 dirs)
    unsigned char* wB8 = (unsigned char*)(ws + 102400000);      //     524,288
    unsigned char* linB8 = (unsigned char*)(ws + 102924288);    //      16,384
    unsigned short* emf = (unsigned short*)(ws + 102940672);    //   2,228,224
    unsigned short* emb = (unsigned short*)(ws + 105168896);    //   2,228,224
    float* llh = (float*)(ws + 107397120);                      //       1,024
    // total: 107,398,144 B (verified footprint)
    // wBihF/wBihB (655,360 B each) alias emf/emb during the GEMM phase only.
    unsigned short* wBihF = emf;
    unsigned short* wBihB = emb;

    prep_w<<<4672, 256, 0, stream>>>(w_hh_f, w_hh_b, lin_w, w_ih_f, w_ih_b,
                                     wB8, linB8, wBihF, wBihB);

    tg_gemm<<<dim3(196, 8), 512, 0, stream>>>(table, wBihF, wBihB,
                                              b_ih_f, b_hh_f, b_ih_b, b_hh_b, tg8);

    lstm_fp8<<<32, 1024, 0, stream>>>(tg8, (const ull*)wB8, words, (const ull*)linB8, emf, emb);

    crf_kernel<<<256, 64, 0, stream>>>(emf, emb, tags, mask, start_trans, end_trans, trans, lin_b, llh);
    final_reduce<<<1, 256, 0, stream>>>(llh, (float*)d_out);
}